// Round 14
// baseline (403.156 us; speedup 1.0000x reference)
//
#include <hip/hip_runtime.h>

#define NN 100000
#define NE 1600000
#define DIMS 32
static constexpr int SCOPIES = 32;

typedef float fx4 __attribute__((ext_vector_type(4)));   // native vec for nontemporal

// bucket partition geometry
#define NBUCK 1024
#define NPB   98          // nodes per bucket: 1024*98 = 100352 >= NN
#define B1    128         // blocks for K1/K3
#define CHUNK (NE / B1)   // 12500

// workspace layout (float offsets)
static constexpr long long OFF_HNB   = 0;          // bf16 hn: NN*32 ushorts = 1.6M float-slots
static constexpr long long OFF_DEGO  = 1600000;    // 100000 ints  [zeroed by k_zero]
static constexpr long long OFF_ESTAT = 1700000;    // 2048 floats  [zeroed]  Σe | Σe²
static constexpr long long OFF_NSTAT = 1702048;    // 2048 floats  [zeroed]  Σw·hn | Σw·hn²
static constexpr long long OFF_SH    = 1704096;    // 2048 floats  [zeroed]  h-stats
static constexpr long long OFF_FIN   = 1706144;    // 128 floats [mh|ih|me|ie]
static constexpr long long OFF_OFFS  = 1706272;    // 100001 ints
static constexpr long long OFF_BBASE = 1806274;    // 1025 ints
static constexpr long long OFF_HIST  = 1807300;    // NBUCK*B1 = 131072 ints
static constexpr long long OFF_REC   = 1938372;    // 1.6M u64 = 3.2M slots (even -> 8B aligned)
static constexpr long long OFF_EID2  = 5138372;    // 1.6M int2 = 3.2M slots (even)

static constexpr long long ZERO_N4 = (OFF_FIN - OFF_DEGO) / 4;   // 26536 float4 slots

__device__ __forceinline__ ushort bf16rn(float f) {
  unsigned u = __float_as_uint(f);
  unsigned r = (u + 0x7FFFu + ((u >> 16) & 1u)) >> 16;
  return (ushort)r;
}
__device__ __forceinline__ float bf16tof(ushort s) {
  return __uint_as_float(((unsigned)s) << 16);
}

// ---------------- k_zero: zero dego+estat+nstat+sh ----------------
__global__ __launch_bounds__(256) void k_zero(float* __restrict__ base) {
  int i = blockIdx.x * blockDim.x + threadIdx.x;
  if (i < ZERO_N4)
    reinterpret_cast<float4*>(base)[i] = make_float4(0.f, 0.f, 0.f, 0.f);
}

// ---------------- kernel A: hnb = bf16(h * norm) ----------------
__global__ __launch_bounds__(256) void k_hn(const float* __restrict__ h,
                                            const float* __restrict__ norm,
                                            ushort* __restrict__ hnb) {
  int i = blockIdx.x * blockDim.x + threadIdx.x;
  if (i >= NN * 8) return;
  float4 v = reinterpret_cast<const float4*>(h)[i];
  float nm = norm[i >> 3];
  ushort4 o;
  o.x = bf16rn(v.x * nm);
  o.y = bf16rn(v.y * nm);
  o.z = bf16rn(v.z * nm);
  o.w = bf16rn(v.w * nm);
  reinterpret_cast<ushort4*>(hnb)[i] = o;
}

// ---------------- k_dego: outdegree histogram (full occupancy) ----------------
__global__ __launch_bounds__(256) void k_dego(const int* __restrict__ src,
                                              int* __restrict__ dego) {
  int i = blockIdx.x * blockDim.x + threadIdx.x;
  if (i >= NE / 4) return;
  int4 s = reinterpret_cast<const int4*>(src)[i];
  atomicAdd(&dego[s.x], 1);
  atomicAdd(&dego[s.y], 1);
  atomicAdd(&dego[s.z], 1);
  atomicAdd(&dego[s.w], 1);
}

// ---------------- k_estat: streamed Σe, Σe² (grid-stride, full occupancy) ----------------
__global__ __launch_bounds__(256) void k_estat(const float* __restrict__ e,
                                               float* __restrict__ estat) {
  __shared__ float sh[64];
  const int t = threadIdx.x;
  if (t < 64) sh[t] = 0.f;
  __syncthreads();
  const float4* e4 = reinterpret_cast<const float4*>(e);
  const int stride = gridDim.x * 256;      // multiple of 8 -> column set fixed per thread
  float s0 = 0.f, s1 = 0.f, s2 = 0.f, s3 = 0.f;
  float q0 = 0.f, q1 = 0.f, q2 = 0.f, q3 = 0.f;
  for (int j = blockIdx.x * 256 + t; j < NE * 8; j += stride) {
    float4 v = e4[j];
    s0 += v.x; s1 += v.y; s2 += v.z; s3 += v.w;
    q0 += v.x * v.x; q1 += v.y * v.y; q2 += v.z * v.z; q3 += v.w * v.w;
  }
  const int cb = (t & 7) * 4;
  atomicAdd(&sh[cb + 0], s0); atomicAdd(&sh[cb + 1], s1);
  atomicAdd(&sh[cb + 2], s2); atomicAdd(&sh[cb + 3], s3);
  atomicAdd(&sh[32 + cb + 0], q0); atomicAdd(&sh[32 + cb + 1], q1);
  atomicAdd(&sh[32 + cb + 2], q2); atomicAdd(&sh[32 + cb + 3], q3);
  __syncthreads();
  if (t < 64) atomicAdd(&estat[(blockIdx.x & (SCOPIES - 1)) * 64 + t], sh[t]);
}

// ---------------- K1: per-block dst-bucket histogram (pure) ----------------
__global__ __launch_bounds__(256) void k_bh(const int* __restrict__ dst,
                                            int* __restrict__ hist) {
  __shared__ int cnt[NBUCK];
  const int t = threadIdx.x, b = blockIdx.x;
  for (int j = t; j < NBUCK; j += 256) cnt[j] = 0;
  __syncthreads();
  const int lo = b * CHUNK, hi = lo + CHUNK;
  for (int i = lo + t; i < hi; i += 256) atomicAdd(&cnt[dst[i] / NPB], 1);
  __syncthreads();
  for (int j = t; j < NBUCK; j += 256) hist[j * B1 + b] = cnt[j];  // [bucket][block]
}

// ---------------- K2: scan bucket totals + per-block offsets ----------------
__global__ __launch_bounds__(1024) void k_bscan(int* __restrict__ hist,
                                                int* __restrict__ bbase) {
  __shared__ int sh[NBUCK];
  const int t = threadIdx.x;   // 1024 = NBUCK
  int tot = 0;
  for (int i = 0; i < B1; ++i) tot += hist[t * B1 + i];
  sh[t] = tot;
  __syncthreads();
  for (int d = 1; d < NBUCK; d <<= 1) {
    int v = (t >= d) ? sh[t - d] : 0;
    __syncthreads();
    sh[t] += v;
    __syncthreads();
  }
  int excl = sh[t] - tot;
  bbase[t] = excl;
  if (t == NBUCK - 1) bbase[NBUCK] = NE;
  int run = excl;
  for (int i = 0; i < B1; ++i) {
    int c = hist[t * B1 + i];
    hist[t * B1 + i] = run;
    run += c;
  }
}

// ---------------- K3: scatter packed records into private regions ----------------
__global__ __launch_bounds__(256) void k_bscat(const int* __restrict__ src,
                                               const int* __restrict__ dst,
                                               const int* __restrict__ hist,
                                               unsigned long long* __restrict__ rec) {
  __shared__ int cur[NBUCK];
  const int t = threadIdx.x, b = blockIdx.x;
  for (int j = t; j < NBUCK; j += 256) cur[j] = hist[j * B1 + b];
  __syncthreads();
  const int lo = b * CHUNK, hi = lo + CHUNK;
  for (int i = lo + t; i < hi; i += 256) {
    int d = dst[i], s = src[i];
    int bk = d / NPB;
    int pos = atomicAdd(&cur[bk], 1);
    rec[pos] = (unsigned long long)i |
               ((unsigned long long)s << 21) |
               ((unsigned long long)d << 38);
  }
}

// ---------------- K4: per-bucket counting sort -> eid2 + offs ----------------
__global__ __launch_bounds__(256) void k_bsort(const unsigned long long* __restrict__ rec,
                                               const int* __restrict__ bbase,
                                               int2* __restrict__ eid2,
                                               int* __restrict__ offs) {
  __shared__ int cnt[NPB];
  __shared__ int curq[NPB];
  __shared__ int2 sorted[2048];
  const int t = threadIdx.x, b = blockIdx.x;
  const int base_e = bbase[b];
  const int n = bbase[b + 1] - base_e;
  const int nodebase = b * NPB;
  if (t < NPB) cnt[t] = 0;
  __syncthreads();
  for (int i = t; i < n; i += 256) {
    int d = (int)((rec[base_e + i] >> 38) & 0x1FFFF);
    atomicAdd(&cnt[d - nodebase], 1);
  }
  __syncthreads();
  if (t == 0) {
    int run = 0;
    for (int j = 0; j < NPB; ++j) {
      int c = cnt[j];
      cnt[j] = run;
      curq[j] = run;
      run += c;
    }
  }
  __syncthreads();
  for (int i = t; i < n; i += 256) {
    unsigned long long r = rec[base_e + i];
    int k = (int)(r & 0x1FFFFF);
    int s = (int)((r >> 21) & 0x1FFFF);
    int d = (int)((r >> 38) & 0x1FFFF);
    int pos = atomicAdd(&curq[d - nodebase], 1);
    if (pos < 2048) sorted[pos] = make_int2(k, s);
  }
  __syncthreads();
  for (int i = t; i < n; i += 256) eid2[base_e + i] = sorted[i];
  for (int j = t; j < NPB; j += 256) {
    int node = nodebase + j;
    if (node < NN) offs[node] = base_e + cnt[j];
  }
  if (b == 0 && t == 0) offs[NN] = NE;
}

// ---------------- k_nstat: degree-weighted node sums for e-stats ----------------
__global__ __launch_bounds__(256) void k_nstat(const ushort* __restrict__ hnb,
                                               const int* __restrict__ dego,
                                               const int* __restrict__ offs,
                                               float* __restrict__ nstat) {
  __shared__ float sh[64];
  const int t = threadIdx.x;
  const int i = blockIdx.x * 256 + t;     // slot over NN*8 (3125 blocks exact)
  if (t < 64) sh[t] = 0.f;
  __syncthreads();
  const int n = i >> 3;
  ushort4 u = reinterpret_cast<const ushort4*>(hnb)[i];
  float w = (float)(dego[n] + (offs[n + 1] - offs[n]));
  float v0 = bf16tof(u.x), v1 = bf16tof(u.y), v2 = bf16tof(u.z), v3 = bf16tof(u.w);
  const int cb = (t & 7) * 4;
  atomicAdd(&sh[cb + 0], w * v0); atomicAdd(&sh[cb + 1], w * v1);
  atomicAdd(&sh[cb + 2], w * v2); atomicAdd(&sh[cb + 3], w * v3);
  atomicAdd(&sh[32 + cb + 0], w * v0 * v0); atomicAdd(&sh[32 + cb + 1], w * v1 * v1);
  atomicAdd(&sh[32 + cb + 2], w * v2 * v2); atomicAdd(&sh[32 + cb + 3], w * v3 * v3);
  __syncthreads();
  if (t < 64) atomicAdd(&nstat[(blockIdx.x & (SCOPIES - 1)) * 64 + t], sh[t]);
}

// ---------------- finalize e-stats (mean exact, var w/o cross terms) ----------------
__global__ void k_fin_e(const float* __restrict__ estat,
                        const float* __restrict__ nstat,
                        float* __restrict__ fin) {
  int t = threadIdx.x;   // 32
  float se = 0.f, qe = 0.f, sw = 0.f, qw = 0.f;
  for (int c = 0; c < SCOPIES; ++c) {
    se += estat[c * 64 + t];
    qe += estat[c * 64 + 32 + t];
    sw += nstat[c * 64 + t];
    qw += nstat[c * 64 + 32 + t];
  }
  float mean = (se + sw) / (float)NE;
  float ex2  = (qe + qw) / (float)NE;
  float var = ex2 - mean * mean;
  fin[64 + t] = mean;
  fin[96 + t] = rsqrtf(var + 1e-5f);
}

// ---- k_agg: gather + FINAL e_out (BN+ReLU) + node update + h-stats ----
__global__ __launch_bounds__(256) void k_agg(const float* __restrict__ e,
                                             const float* __restrict__ h,
                                             const ushort* __restrict__ hnb,
                                             const int* __restrict__ offs,
                                             const int2* __restrict__ eid2,
                                             const float* __restrict__ norm,
                                             const float* __restrict__ fin,
                                             const float* __restrict__ ge,
                                             const float* __restrict__ be,
                                             float* __restrict__ hpre,
                                             float* __restrict__ eout,
                                             float* __restrict__ stats_h) {
  const int g = (blockIdx.x * blockDim.x + threadIdx.x) >> 3;
  const int lane = threadIdx.x & 7;
  const int cb = lane * 4;
  float n0 = 0.f, n1 = 0.f, n2 = 0.f, n3 = 0.f;
  float d0 = 0.f, d1 = 0.f, d2 = 0.f, d3 = 0.f;

  const float4*  e4  = reinterpret_cast<const float4*>(e);
  const ushort4* hb4 = reinterpret_cast<const ushort4*>(hnb);

  float me0 = fin[64 + cb + 0], me1 = fin[64 + cb + 1], me2 = fin[64 + cb + 2], me3 = fin[64 + cb + 3];
  float ie0 = fin[96 + cb + 0], ie1 = fin[96 + cb + 1], ie2 = fin[96 + cb + 2], ie3 = fin[96 + cb + 3];
  float ge0 = ge[cb + 0], ge1 = ge[cb + 1], ge2 = ge[cb + 2], ge3 = ge[cb + 3];
  float be0 = be[cb + 0], be1 = be[cb + 1], be2 = be[cb + 2], be3 = be[cb + 3];

  ushort4 uhv = hb4[(long long)g * 8 + lane];
  float hv0 = bf16tof(uhv.x), hv1 = bf16tof(uhv.y), hv2 = bf16tof(uhv.z), hv3 = bf16tof(uhv.w);
  float nm = norm[g];
  float4 hf = reinterpret_cast<const float4*>(h)[(long long)g * 8 + lane];
  float hw0 = hf.x * nm, hw1 = hf.y * nm, hw2 = hf.z * nm, hw3 = hf.w * nm;

  const int lo = offs[g];
  const int hi = offs[g + 1];

#define AGG_CONSUME(EV, US, KX)                                                   \
  {                                                                               \
    float fs0 = bf16tof(US.x), fs1 = bf16tof(US.y),                               \
          fs2 = bf16tof(US.z), fs3 = bf16tof(US.w);                               \
    float x0 = EV.x + fs0 + hv0;                                                  \
    float x1 = EV.y + fs1 + hv1;                                                  \
    float x2 = EV.z + fs2 + hv2;                                                  \
    float x3 = EV.w + fs3 + hv3;                                                  \
    float g0 = 1.f / (1.f + __expf(-x0));                                         \
    float g1 = 1.f / (1.f + __expf(-x1));                                         \
    float g2 = 1.f / (1.f + __expf(-x2));                                         \
    float g3 = 1.f / (1.f + __expf(-x3));                                         \
    n0 += g0 * fs0; n1 += g1 * fs1; n2 += g2 * fs2; n3 += g3 * fs3;               \
    d0 += g0; d1 += g1; d2 += g2; d3 += g3;                                       \
    fx4 ov;                                                                       \
    ov.x = fmaxf(0.f, (x0 - me0) * ie0 * ge0 + be0);                              \
    ov.y = fmaxf(0.f, (x1 - me1) * ie1 * ge1 + be1);                              \
    ov.z = fmaxf(0.f, (x2 - me2) * ie2 * ge2 + be2);                              \
    ov.w = fmaxf(0.f, (x3 - me3) * ie3 * ge3 + be3);                              \
    __builtin_nontemporal_store(ov, reinterpret_cast<fx4*>(eout) + ((long long)(KX) * 8 + lane)); \
  }

  int p = lo;
  for (; p + 4 <= hi; p += 4) {
    int2 r0 = eid2[p + 0];
    int2 r1 = eid2[p + 1];
    int2 r2 = eid2[p + 2];
    int2 r3 = eid2[p + 3];
    float4  ev0 = e4[(long long)r0.x * 8 + lane];
    float4  ev1 = e4[(long long)r1.x * 8 + lane];
    float4  ev2 = e4[(long long)r2.x * 8 + lane];
    float4  ev3 = e4[(long long)r3.x * 8 + lane];
    ushort4 us0 = hb4[(long long)r0.y * 8 + lane];
    ushort4 us1 = hb4[(long long)r1.y * 8 + lane];
    ushort4 us2 = hb4[(long long)r2.y * 8 + lane];
    ushort4 us3 = hb4[(long long)r3.y * 8 + lane];
    AGG_CONSUME(ev0, us0, r0.x)
    AGG_CONSUME(ev1, us1, r1.x)
    AGG_CONSUME(ev2, us2, r2.x)
    AGG_CONSUME(ev3, us3, r3.x)
  }
  for (; p < hi; ++p) {
    int2 r0 = eid2[p];
    float4  ev0 = e4[(long long)r0.x * 8 + lane];
    ushort4 us0 = hb4[(long long)r0.y * 8 + lane];
    AGG_CONSUME(ev0, us0, r0.x)
  }
#undef AGG_CONSUME

  float y0 = (hw0 + n0 / (d0 + 1e-6f)) * nm;
  float y1 = (hw1 + n1 / (d1 + 1e-6f)) * nm;
  float y2 = (hw2 + n2 / (d2 + 1e-6f)) * nm;
  float y3 = (hw3 + n3 / (d3 + 1e-6f)) * nm;
  reinterpret_cast<float4*>(hpre)[(long long)g * 8 + lane] = make_float4(y0, y1, y2, y3);

  __shared__ float sh[64];
  if (threadIdx.x < 64) sh[threadIdx.x] = 0.f;
  __syncthreads();
  atomicAdd(&sh[cb + 0], y0); atomicAdd(&sh[cb + 1], y1);
  atomicAdd(&sh[cb + 2], y2); atomicAdd(&sh[cb + 3], y3);
  atomicAdd(&sh[32 + cb + 0], y0 * y0); atomicAdd(&sh[32 + cb + 1], y1 * y1);
  atomicAdd(&sh[32 + cb + 2], y2 * y2); atomicAdd(&sh[32 + cb + 3], y3 * y3);
  __syncthreads();
  if (threadIdx.x < 64)
    atomicAdd(&stats_h[(blockIdx.x & (SCOPIES - 1)) * 64 + threadIdx.x], sh[threadIdx.x]);
}

// ---------------- finalize h-stats ----------------
__global__ void k_fin_h(const float* __restrict__ stats_h, float* __restrict__ fin) {
  int t = threadIdx.x;   // 32
  float s = 0.f, q = 0.f;
  for (int c = 0; c < SCOPIES; ++c) {
    s += stats_h[c * 64 + t];
    q += stats_h[c * 64 + 32 + t];
  }
  float mean = s / (float)NN;
  float var = q / (float)NN - mean * mean;
  fin[t] = mean;
  fin[32 + t] = rsqrtf(var + 1e-5f);
}

// ---------------- in-place BN + ReLU apply (h only) ----------------
__global__ __launch_bounds__(256) void k_apply(float* __restrict__ buf,
                                               long long nslots,
                                               const float* __restrict__ mean,
                                               const float* __restrict__ inv,
                                               const float* __restrict__ gamma,
                                               const float* __restrict__ beta) {
  long long i = (long long)blockIdx.x * blockDim.x + threadIdx.x;
  if (i >= nslots) return;
  const int cb = (int)(i & 7) * 4;
  float4 x = reinterpret_cast<float4*>(buf)[i];
  float y0 = fmaxf(0.f, (x.x - mean[cb + 0]) * inv[cb + 0] * gamma[cb + 0] + beta[cb + 0]);
  float y1 = fmaxf(0.f, (x.y - mean[cb + 1]) * inv[cb + 1] * gamma[cb + 1] + beta[cb + 1]);
  float y2 = fmaxf(0.f, (x.z - mean[cb + 2]) * inv[cb + 2] * gamma[cb + 2] + beta[cb + 2]);
  float y3 = fmaxf(0.f, (x.w - mean[cb + 3]) * inv[cb + 3] * gamma[cb + 3] + beta[cb + 3]);
  reinterpret_cast<float4*>(buf)[i] = make_float4(y0, y1, y2, y3);
}

extern "C" void kernel_launch(void* const* d_in, const int* in_sizes, int n_in,
                              void* d_out, int out_size, void* d_ws, size_t ws_size,
                              hipStream_t stream) {
  const float* h     = (const float*)d_in[0];
  const float* e     = (const float*)d_in[1];
  const float* norm  = (const float*)d_in[2];
  const int*   src   = (const int*)d_in[3];
  const int*   dst   = (const int*)d_in[4];
  const float* gh    = (const float*)d_in[5];
  const float* bh    = (const float*)d_in[6];
  const float* ge    = (const float*)d_in[7];
  const float* be    = (const float*)d_in[8];
  (void)in_sizes; (void)n_in; (void)out_size; (void)ws_size;

  float*  ws    = (float*)d_ws;
  ushort* hnb   = (ushort*)(ws + OFF_HNB);
  int*    dego  = (int*)(ws + OFF_DEGO);
  float*  estat = ws + OFF_ESTAT;
  float*  nstat = ws + OFF_NSTAT;
  float*  shh   = ws + OFF_SH;
  float*  fin   = ws + OFF_FIN;
  int*    offs  = (int*)(ws + OFF_OFFS);
  int*    bbase = (int*)(ws + OFF_BBASE);
  int*    hist  = (int*)(ws + OFF_HIST);
  unsigned long long* rec = (unsigned long long*)(ws + OFF_REC);
  int2*   eid2  = (int2*)(ws + OFF_EID2);

  float* out  = (float*)d_out;
  float* hpre = out;                           // [NN*32] h output region
  float* eout = out + (long long)NN * DIMS;    // [NE*32] final e output

  k_zero<<<(int)((ZERO_N4 + 255) / 256), 256, 0, stream>>>(ws + OFF_DEGO);
  k_hn<<<(NN * 8 + 255) / 256, 256, 0, stream>>>(h, norm, hnb);
  k_dego<<<(NE / 4 + 255) / 256, 256, 0, stream>>>(src, dego);
  k_estat<<<2048, 256, 0, stream>>>(e, estat);
  k_bh<<<B1, 256, 0, stream>>>(dst, hist);
  k_bscan<<<1, NBUCK, 0, stream>>>(hist, bbase);
  k_bscat<<<B1, 256, 0, stream>>>(src, dst, hist, rec);
  k_bsort<<<NBUCK, 256, 0, stream>>>(rec, bbase, eid2, offs);
  k_nstat<<<NN * 8 / 256, 256, 0, stream>>>(hnb, dego, offs, nstat);
  k_fin_e<<<1, 32, 0, stream>>>(estat, nstat, fin);
  k_agg<<<NN * 8 / 256, 256, 0, stream>>>(e, h, hnb, offs, eid2, norm, fin, ge, be,
                                          hpre, eout, shh);
  k_fin_h<<<1, 32, 0, stream>>>(shh, fin);
  k_apply<<<(NN * 8 + 255) / 256, 256, 0, stream>>>(hpre, (long long)NN * 8,
                                                    fin + 0, fin + 32, gh, bh);
}

// Round 15
// 321.784 us; speedup vs baseline: 1.2529x; 1.2529x over previous
//
#include <hip/hip_runtime.h>

#define NN 100000
#define NE 1600000
#define DIMS 32
static constexpr int SCOPIES = 32;

typedef float fx4 __attribute__((ext_vector_type(4)));   // native vec for nontemporal

// hierarchical scan geometry
#define SCAN_NB  128
#define SCAN_NTH 256
#define SCAN_CPT 4    // 128*256*4 = 131072 >= 100000

// workspace layout (float offsets)
static constexpr long long OFF_HNB  = 0;          // bf16 hn: NN*32 ushorts = 1.6M float-slots
static constexpr long long OFF_DEG  = 1600000;    // 100000 ints   [zeroed]
static constexpr long long OFF_SE   = 1700000;    // 2048 floats   [zeroed]
static constexpr long long OFF_SH   = 1702048;    // 2048 floats   [zeroed]
static constexpr long long OFF_FIN  = 1704096;    // 128 floats: [mh|ih|me|ie]
static constexpr long long OFF_OFFS = 1704224;    // 100001 ints
static constexpr long long OFF_CURS = 1804232;    // 100000 ints
static constexpr long long OFF_TEX  = 1904232;    // 32768 ints
static constexpr long long OFF_PART = 1937000;    // 128 ints
static constexpr long long OFF_EID2 = 1937128;    // 3.2M ints (1.6M int2), 8B-aligned

static constexpr long long ZERO_N4 = (OFF_FIN - OFF_DEG) / 4;   // deg+se+sh region

__device__ __forceinline__ ushort bf16rn(float f) {
  unsigned u = __float_as_uint(f);
  unsigned r = (u + 0x7FFFu + ((u >> 16) & 1u)) >> 16;
  return (ushort)r;
}
__device__ __forceinline__ float bf16tof(ushort s) {
  return __uint_as_float(((unsigned)s) << 16);
}

// ---------------- k_zero: zero deg+se+sh ----------------
__global__ __launch_bounds__(256) void k_zero(float* __restrict__ base) {
  int i = blockIdx.x * blockDim.x + threadIdx.x;
  if (i < ZERO_N4)
    reinterpret_cast<float4*>(base)[i] = make_float4(0.f, 0.f, 0.f, 0.f);
}

// ---------------- kernel A: hnb = bf16(h * norm) ----------------
__global__ __launch_bounds__(256) void k_hn(const float* __restrict__ h,
                                            const float* __restrict__ norm,
                                            ushort* __restrict__ hnb) {
  int i = blockIdx.x * blockDim.x + threadIdx.x;
  if (i >= NN * 8) return;
  float4 v = reinterpret_cast<const float4*>(h)[i];
  float nm = norm[i >> 3];
  ushort4 o;
  o.x = bf16rn(v.x * nm);
  o.y = bf16rn(v.y * nm);
  o.z = bf16rn(v.z * nm);
  o.w = bf16rn(v.w * nm);
  reinterpret_cast<ushort4*>(hnb)[i] = o;
}

// ---------------- kernel H: dst-degree histogram ----------------
__global__ __launch_bounds__(256) void k_hist(const int* __restrict__ dst,
                                              int* __restrict__ deg) {
  int i = blockIdx.x * blockDim.x + threadIdx.x;
  if (i >= NE / 4) return;
  int4 d = reinterpret_cast<const int4*>(dst)[i];
  atomicAdd(&deg[d.x], 1);
  atomicAdd(&deg[d.y], 1);
  atomicAdd(&deg[d.z], 1);
  atomicAdd(&deg[d.w], 1);
}

// ---------------- scan phase A ----------------
__global__ __launch_bounds__(SCAN_NTH) void k_scanA(const int* __restrict__ deg,
                                                    int* __restrict__ texcl,
                                                    int* __restrict__ partials) {
  const int t = threadIdx.x, b = blockIdx.x;
  const int tid = b * SCAN_NTH + t;
  const int lo = tid * SCAN_CPT;
  const int hi = (lo + SCAN_CPT < NN) ? lo + SCAN_CPT : NN;
  int s = 0;
  for (int i = lo; i < hi; ++i) s += deg[i];
  __shared__ int sh[SCAN_NTH];
  sh[t] = s;
  __syncthreads();
  for (int d = 1; d < SCAN_NTH; d <<= 1) {
    int v = (t >= d) ? sh[t - d] : 0;
    __syncthreads();
    sh[t] += v;
    __syncthreads();
  }
  texcl[b * SCAN_NTH + t] = sh[t] - s;
  if (t == SCAN_NTH - 1) partials[b] = sh[t];
}

// ---------------- scan phase B ----------------
__global__ __launch_bounds__(SCAN_NB) void k_scanB(int* __restrict__ partials) {
  __shared__ int sh[SCAN_NB];
  const int t = threadIdx.x;
  int v = partials[t];
  sh[t] = v;
  __syncthreads();
  for (int d = 1; d < SCAN_NB; d <<= 1) {
    int u = (t >= d) ? sh[t - d] : 0;
    __syncthreads();
    sh[t] += u;
    __syncthreads();
  }
  partials[t] = sh[t] - v;
}

// ---------------- scan phase C ----------------
__global__ __launch_bounds__(SCAN_NTH) void k_scanC(const int* __restrict__ deg,
                                                    const int* __restrict__ texcl,
                                                    const int* __restrict__ partials,
                                                    int* __restrict__ offs,
                                                    int* __restrict__ curs) {
  const int t = threadIdx.x, b = blockIdx.x;
  const int tid = b * SCAN_NTH + t;
  const int lo = tid * SCAN_CPT;
  const int hi = (lo + SCAN_CPT < NN) ? lo + SCAN_CPT : NN;
  int run = partials[b] + texcl[b * SCAN_NTH + t];
  for (int i = lo; i < hi; ++i) {
    offs[i] = run;
    curs[i] = run;
    run += deg[i];
  }
  if (tid == 0) offs[NN] = NE;
}

// ---- kernel B: e-stats + fused CSR scatter; 4-edge batched MLP ----
__global__ __launch_bounds__(256) void k_edge(const float* __restrict__ e,
                                              const ushort* __restrict__ hnb,
                                              const int* __restrict__ src,
                                              const int* __restrict__ dst,
                                              int* __restrict__ curs,
                                              int2* __restrict__ eid2,
                                              float* __restrict__ stats_e) {
  const int lane = threadIdx.x & 7;                 // 8 threads per edge
  const int slot0 = (blockIdx.x * blockDim.x + threadIdx.x) >> 3;
  const int S = (gridDim.x * blockDim.x) >> 3;      // nslots
  float s0 = 0.f, s1 = 0.f, s2 = 0.f, s3 = 0.f;
  float q0 = 0.f, q1 = 0.f, q2 = 0.f, q3 = 0.f;

  const float4*  e4  = reinterpret_cast<const float4*>(e);
  const ushort4* hb4 = reinterpret_cast<const ushort4*>(hnb);

  for (int base = slot0; base < NE; base += 4 * S) {
    const int k0 = base;
    const int k1 = base + S;
    const int k2 = base + 2 * S;
    const int k3 = base + 3 * S;
    const bool v1 = (k1 < NE), v2 = (k2 < NE), v3 = (k3 < NE);
    const int a1 = v1 ? k1 : k0, a2 = v2 ? k2 : k0, a3 = v3 ? k3 : k0;
    // load all ids (independent)
    const int sc0 = src[k0], dc0 = dst[k0];
    const int sc1 = src[a1], dc1 = dst[a1];
    const int sc2 = src[a2], dc2 = dst[a2];
    const int sc3 = src[a3], dc3 = dst[a3];
    // issue all gathers back-to-back (12 independent requests)
    float4  ev0 = e4[(long long)k0 * 8 + lane];
    float4  ev1 = e4[(long long)a1 * 8 + lane];
    float4  ev2 = e4[(long long)a2 * 8 + lane];
    float4  ev3 = e4[(long long)a3 * 8 + lane];
    ushort4 hs0 = hb4[(long long)sc0 * 8 + lane];
    ushort4 hs1 = hb4[(long long)sc1 * 8 + lane];
    ushort4 hs2 = hb4[(long long)sc2 * 8 + lane];
    ushort4 hs3 = hb4[(long long)sc3 * 8 + lane];
    ushort4 hd0 = hb4[(long long)dc0 * 8 + lane];
    ushort4 hd1 = hb4[(long long)dc1 * 8 + lane];
    ushort4 hd2 = hb4[(long long)dc2 * 8 + lane];
    ushort4 hd3 = hb4[(long long)dc3 * 8 + lane];
    // scatter (lane 0), guarded per edge
    if (lane == 0) {
      { int pos = atomicAdd(&curs[dc0], 1); eid2[pos] = make_int2(k0, sc0); }
      if (v1) { int pos = atomicAdd(&curs[dc1], 1); eid2[pos] = make_int2(k1, sc1); }
      if (v2) { int pos = atomicAdd(&curs[dc2], 1); eid2[pos] = make_int2(k2, sc2); }
      if (v3) { int pos = atomicAdd(&curs[dc3], 1); eid2[pos] = make_int2(k3, sc3); }
    }
    // consume
    {
      float x0 = ev0.x + bf16tof(hs0.x) + bf16tof(hd0.x);
      float x1 = ev0.y + bf16tof(hs0.y) + bf16tof(hd0.y);
      float x2 = ev0.z + bf16tof(hs0.z) + bf16tof(hd0.z);
      float x3 = ev0.w + bf16tof(hs0.w) + bf16tof(hd0.w);
      s0 += x0; s1 += x1; s2 += x2; s3 += x3;
      q0 += x0 * x0; q1 += x1 * x1; q2 += x2 * x2; q3 += x3 * x3;
    }
    if (v1) {
      float x0 = ev1.x + bf16tof(hs1.x) + bf16tof(hd1.x);
      float x1 = ev1.y + bf16tof(hs1.y) + bf16tof(hd1.y);
      float x2 = ev1.z + bf16tof(hs1.z) + bf16tof(hd1.z);
      float x3 = ev1.w + bf16tof(hs1.w) + bf16tof(hd1.w);
      s0 += x0; s1 += x1; s2 += x2; s3 += x3;
      q0 += x0 * x0; q1 += x1 * x1; q2 += x2 * x2; q3 += x3 * x3;
    }
    if (v2) {
      float x0 = ev2.x + bf16tof(hs2.x) + bf16tof(hd2.x);
      float x1 = ev2.y + bf16tof(hs2.y) + bf16tof(hd2.y);
      float x2 = ev2.z + bf16tof(hs2.z) + bf16tof(hd2.z);
      float x3 = ev2.w + bf16tof(hs2.w) + bf16tof(hd2.w);
      s0 += x0; s1 += x1; s2 += x2; s3 += x3;
      q0 += x0 * x0; q1 += x1 * x1; q2 += x2 * x2; q3 += x3 * x3;
    }
    if (v3) {
      float x0 = ev3.x + bf16tof(hs3.x) + bf16tof(hd3.x);
      float x1 = ev3.y + bf16tof(hs3.y) + bf16tof(hd3.y);
      float x2 = ev3.z + bf16tof(hs3.z) + bf16tof(hd3.z);
      float x3 = ev3.w + bf16tof(hs3.w) + bf16tof(hd3.w);
      s0 += x0; s1 += x1; s2 += x2; s3 += x3;
      q0 += x0 * x0; q1 += x1 * x1; q2 += x2 * x2; q3 += x3 * x3;
    }
  }

  __shared__ float sh[64];
  if (threadIdx.x < 64) sh[threadIdx.x] = 0.f;
  __syncthreads();
  const int cb = lane * 4;
  atomicAdd(&sh[cb + 0], s0); atomicAdd(&sh[cb + 1], s1);
  atomicAdd(&sh[cb + 2], s2); atomicAdd(&sh[cb + 3], s3);
  atomicAdd(&sh[32 + cb + 0], q0); atomicAdd(&sh[32 + cb + 1], q1);
  atomicAdd(&sh[32 + cb + 2], q2); atomicAdd(&sh[32 + cb + 3], q3);
  __syncthreads();
  if (threadIdx.x < 64)
    atomicAdd(&stats_e[(blockIdx.x & (SCOPIES - 1)) * 64 + threadIdx.x], sh[threadIdx.x]);
}

// ---------------- finalize e-stats ----------------
__global__ void k_fin_e(const float* __restrict__ stats_e, float* __restrict__ fin) {
  int t = threadIdx.x;   // 32 threads
  float s = 0.f, q = 0.f;
  for (int c = 0; c < SCOPIES; ++c) {
    s += stats_e[c * 64 + t];
    q += stats_e[c * 64 + 32 + t];
  }
  float mean = s / (float)NE;
  float var = q / (float)NE - mean * mean;
  fin[64 + t] = mean;
  fin[96 + t] = rsqrtf(var + 1e-5f);
}

// ---- kernel E: gather-aggregate + node update + h-stats + e_out, 4-batched ----
__global__ __launch_bounds__(256) void k_agg(const float* __restrict__ e,
                                             const float* __restrict__ h,
                                             const ushort* __restrict__ hnb,
                                             const int* __restrict__ offs,
                                             const int2* __restrict__ eid2,
                                             const float* __restrict__ norm,
                                             const float* __restrict__ fin,
                                             const float* __restrict__ ge,
                                             const float* __restrict__ be,
                                             float* __restrict__ hpre,
                                             float* __restrict__ eout,
                                             float* __restrict__ stats_h) {
  const int g = (blockIdx.x * blockDim.x + threadIdx.x) >> 3;  // node id (3125 blocks)
  const int lane = threadIdx.x & 7;
  const int cb = lane * 4;
  float n0 = 0.f, n1 = 0.f, n2 = 0.f, n3 = 0.f;
  float d0 = 0.f, d1 = 0.f, d2 = 0.f, d3 = 0.f;

  const float4*  e4  = reinterpret_cast<const float4*>(e);
  const ushort4* hb4 = reinterpret_cast<const ushort4*>(hnb);

  float me0 = fin[64 + cb + 0], me1 = fin[64 + cb + 1], me2 = fin[64 + cb + 2], me3 = fin[64 + cb + 3];
  float ie0 = fin[96 + cb + 0], ie1 = fin[96 + cb + 1], ie2 = fin[96 + cb + 2], ie3 = fin[96 + cb + 3];
  float ge0 = ge[cb + 0], ge1 = ge[cb + 1], ge2 = ge[cb + 2], ge3 = ge[cb + 3];
  float be0 = be[cb + 0], be1 = be[cb + 1], be2 = be[cb + 2], be3 = be[cb + 3];

  ushort4 uhv = hb4[(long long)g * 8 + lane];
  float hv0 = bf16tof(uhv.x), hv1 = bf16tof(uhv.y), hv2 = bf16tof(uhv.z), hv3 = bf16tof(uhv.w);
  float nm = norm[g];
  float4 hf = reinterpret_cast<const float4*>(h)[(long long)g * 8 + lane];
  float hw0 = hf.x * nm, hw1 = hf.y * nm, hw2 = hf.z * nm, hw3 = hf.w * nm;

  const int lo = offs[g];
  const int hi = offs[g + 1];

#define AGG_CONSUME(EV, US, KX)                                                   \
  {                                                                               \
    float fs0 = bf16tof(US.x), fs1 = bf16tof(US.y),                               \
          fs2 = bf16tof(US.z), fs3 = bf16tof(US.w);                               \
    float x0 = EV.x + fs0 + hv0;                                                  \
    float x1 = EV.y + fs1 + hv1;                                                  \
    float x2 = EV.z + fs2 + hv2;                                                  \
    float x3 = EV.w + fs3 + hv3;                                                  \
    float g0 = 1.f / (1.f + __expf(-x0));                                         \
    float g1 = 1.f / (1.f + __expf(-x1));                                         \
    float g2 = 1.f / (1.f + __expf(-x2));                                         \
    float g3 = 1.f / (1.f + __expf(-x3));                                         \
    n0 += g0 * fs0; n1 += g1 * fs1; n2 += g2 * fs2; n3 += g3 * fs3;               \
    d0 += g0; d1 += g1; d2 += g2; d3 += g3;                                       \
    fx4 ov;                                                                       \
    ov.x = fmaxf(0.f, (x0 - me0) * ie0 * ge0 + be0);                              \
    ov.y = fmaxf(0.f, (x1 - me1) * ie1 * ge1 + be1);                              \
    ov.z = fmaxf(0.f, (x2 - me2) * ie2 * ge2 + be2);                              \
    ov.w = fmaxf(0.f, (x3 - me3) * ie3 * ge3 + be3);                              \
    __builtin_nontemporal_store(ov, reinterpret_cast<fx4*>(eout) + ((long long)(KX) * 8 + lane)); \
  }

  int p = lo;
  for (; p + 4 <= hi; p += 4) {
    int2 r0 = eid2[p + 0];
    int2 r1 = eid2[p + 1];
    int2 r2 = eid2[p + 2];
    int2 r3 = eid2[p + 3];
    float4  ev0 = e4[(long long)r0.x * 8 + lane];
    float4  ev1 = e4[(long long)r1.x * 8 + lane];
    float4  ev2 = e4[(long long)r2.x * 8 + lane];
    float4  ev3 = e4[(long long)r3.x * 8 + lane];
    ushort4 us0 = hb4[(long long)r0.y * 8 + lane];
    ushort4 us1 = hb4[(long long)r1.y * 8 + lane];
    ushort4 us2 = hb4[(long long)r2.y * 8 + lane];
    ushort4 us3 = hb4[(long long)r3.y * 8 + lane];
    AGG_CONSUME(ev0, us0, r0.x)
    AGG_CONSUME(ev1, us1, r1.x)
    AGG_CONSUME(ev2, us2, r2.x)
    AGG_CONSUME(ev3, us3, r3.x)
  }
  for (; p < hi; ++p) {
    int2 r0 = eid2[p];
    float4  ev0 = e4[(long long)r0.x * 8 + lane];
    ushort4 us0 = hb4[(long long)r0.y * 8 + lane];
    AGG_CONSUME(ev0, us0, r0.x)
  }
#undef AGG_CONSUME

  float y0 = (hw0 + n0 / (d0 + 1e-6f)) * nm;
  float y1 = (hw1 + n1 / (d1 + 1e-6f)) * nm;
  float y2 = (hw2 + n2 / (d2 + 1e-6f)) * nm;
  float y3 = (hw3 + n3 / (d3 + 1e-6f)) * nm;
  reinterpret_cast<float4*>(hpre)[(long long)g * 8 + lane] = make_float4(y0, y1, y2, y3);

  __shared__ float sh[64];
  if (threadIdx.x < 64) sh[threadIdx.x] = 0.f;
  __syncthreads();
  atomicAdd(&sh[cb + 0], y0); atomicAdd(&sh[cb + 1], y1);
  atomicAdd(&sh[cb + 2], y2); atomicAdd(&sh[cb + 3], y3);
  atomicAdd(&sh[32 + cb + 0], y0 * y0); atomicAdd(&sh[32 + cb + 1], y1 * y1);
  atomicAdd(&sh[32 + cb + 2], y2 * y2); atomicAdd(&sh[32 + cb + 3], y3 * y3);
  __syncthreads();
  if (threadIdx.x < 64)
    atomicAdd(&stats_h[(blockIdx.x & (SCOPIES - 1)) * 64 + threadIdx.x], sh[threadIdx.x]);
}

// ---------------- finalize h-stats ----------------
__global__ void k_fin_h(const float* __restrict__ stats_h, float* __restrict__ fin) {
  int t = threadIdx.x;   // 32 threads
  float s = 0.f, q = 0.f;
  for (int c = 0; c < SCOPIES; ++c) {
    s += stats_h[c * 64 + t];
    q += stats_h[c * 64 + 32 + t];
  }
  float mean = s / (float)NN;
  float var = q / (float)NN - mean * mean;
  fin[t] = mean;
  fin[32 + t] = rsqrtf(var + 1e-5f);
}

// ---------------- in-place BN + ReLU apply (h only) ----------------
__global__ __launch_bounds__(256) void k_apply(float* __restrict__ buf,
                                               long long nslots,
                                               const float* __restrict__ mean,
                                               const float* __restrict__ inv,
                                               const float* __restrict__ gamma,
                                               const float* __restrict__ beta) {
  long long i = (long long)blockIdx.x * blockDim.x + threadIdx.x;
  if (i >= nslots) return;
  const int cb = (int)(i & 7) * 4;
  float4 x = reinterpret_cast<float4*>(buf)[i];
  float y0 = fmaxf(0.f, (x.x - mean[cb + 0]) * inv[cb + 0] * gamma[cb + 0] + beta[cb + 0]);
  float y1 = fmaxf(0.f, (x.y - mean[cb + 1]) * inv[cb + 1] * gamma[cb + 1] + beta[cb + 1]);
  float y2 = fmaxf(0.f, (x.z - mean[cb + 2]) * inv[cb + 2] * gamma[cb + 2] + beta[cb + 2]);
  float y3 = fmaxf(0.f, (x.w - mean[cb + 3]) * inv[cb + 3] * gamma[cb + 3] + beta[cb + 3]);
  reinterpret_cast<float4*>(buf)[i] = make_float4(y0, y1, y2, y3);
}

extern "C" void kernel_launch(void* const* d_in, const int* in_sizes, int n_in,
                              void* d_out, int out_size, void* d_ws, size_t ws_size,
                              hipStream_t stream) {
  const float* h     = (const float*)d_in[0];
  const float* e     = (const float*)d_in[1];
  const float* norm  = (const float*)d_in[2];
  const int*   src   = (const int*)d_in[3];
  const int*   dst   = (const int*)d_in[4];
  const float* gh    = (const float*)d_in[5];
  const float* bh    = (const float*)d_in[6];
  const float* ge    = (const float*)d_in[7];
  const float* be    = (const float*)d_in[8];
  (void)in_sizes; (void)n_in; (void)out_size; (void)ws_size;

  float*  ws    = (float*)d_ws;
  ushort* hnb   = (ushort*)(ws + OFF_HNB);
  int*    deg   = (int*)(ws + OFF_DEG);
  float*  se    = ws + OFF_SE;
  float*  shh   = ws + OFF_SH;
  float*  fin   = ws + OFF_FIN;
  int*    offs  = (int*)(ws + OFF_OFFS);
  int*    curs  = (int*)(ws + OFF_CURS);
  int*    texcl = (int*)(ws + OFF_TEX);
  int*    parts = (int*)(ws + OFF_PART);
  int2*   eid2  = (int2*)(ws + OFF_EID2);

  float* out  = (float*)d_out;
  float* hpre = out;                           // [NN*32] h output region
  float* eout = out + (long long)NN * DIMS;    // [NE*32] final e output

  k_zero<<<(int)((ZERO_N4 + 255) / 256), 256, 0, stream>>>(ws + OFF_DEG);
  k_hn<<<(NN * 8 + 255) / 256, 256, 0, stream>>>(h, norm, hnb);
  k_hist<<<(NE / 4 + 255) / 256, 256, 0, stream>>>(dst, deg);
  k_scanA<<<SCAN_NB, SCAN_NTH, 0, stream>>>(deg, texcl, parts);
  k_scanB<<<1, SCAN_NB, 0, stream>>>(parts);
  k_scanC<<<SCAN_NB, SCAN_NTH, 0, stream>>>(deg, texcl, parts, offs, curs);
  k_edge<<<4096, 256, 0, stream>>>(e, hnb, src, dst, curs, eid2, se);
  k_fin_e<<<1, 32, 0, stream>>>(se, fin);
  k_agg<<<NN * 8 / 256, 256, 0, stream>>>(e, h, hnb, offs, eid2, norm, fin, ge, be,
                                          hpre, eout, shh);
  k_fin_h<<<1, 32, 0, stream>>>(shh, fin);
  k_apply<<<(NN * 8 + 255) / 256, 256, 0, stream>>>(hpre, (long long)NN * 8,
                                                    fin + 0, fin + 32, gh, bh);
}